// Round 4
// baseline (140456.995 us; speedup 1.0000x reference)
//
#include <hip/hip_runtime.h>

#define HID 512
#define NB  64
#define NT  1024
#define THX 0.1f
#define THH 0.05f
#define CH  16   // pipeline chunk (entries per chunk, 2 chunks in flight)

// ---- prep: pack W_ih_l0 [1536][6] f32 -> [6][512][4] f32 (r,z,n,0 per j) ----
__global__ void pack_ih0(const float* __restrict__ src, float* __restrict__ dst) {
    int idx = blockIdx.x * blockDim.x + threadIdx.x;
    if (idx < 6 * HID) {
        int f = idx / HID, j = idx % HID;
        dst[f * 2048 + j * 4 + 0] = src[(0 * HID + j) * 6 + f];
        dst[f * 2048 + j * 4 + 1] = src[(1 * HID + j) * 6 + f];
        dst[f * 2048 + j * 4 + 2] = src[(2 * HID + j) * 6 + f];
        dst[f * 2048 + j * 4 + 3] = 0.f;
    }
}

// ---- prep: pack a [1536][512] f32 matrix -> [512(k)][512(j)][4] f32 ----
__global__ void pack_h4(const float* __restrict__ src, float* __restrict__ dst) {
    int idx = blockIdx.x * blockDim.x + threadIdx.x;
    if (idx < HID * HID) {
        int k = idx / HID, j = idx % HID;
        dst[k * 2048 + j * 4 + 0] = src[(0 * HID + j) * HID + k];
        dst[k * 2048 + j * 4 + 1] = src[(1 * HID + j) * HID + k];
        dst[k * 2048 + j * 4 + 2] = src[(2 * HID + j) * HID + k];
        dst[k * 2048 + j * 4 + 3] = 0.f;
    }
}

// ---- pipelined sparse MAC helper ----
// lst: compacted (k, val) entries, zero-padded to n (multiple of 32).
// wp:  packed [512][512] float4 matrix; row k at byte offset k<<13.
// Accumulates ar += v*w.x, az += v*w.y, a3 += v*w.z over entries in order.
__device__ __forceinline__ void load_chunk(const uint2* __restrict__ lst, int ch,
                                           const float4* __restrict__ wp, int j,
                                           float* v, float4* w) {
    uint2 e[CH];
    #pragma unroll
    for (int c = 0; c < CH; ++c) e[c] = lst[ch * CH + c];
    #pragma unroll
    for (int c = 0; c < CH; ++c) {
        int kk = __builtin_amdgcn_readfirstlane((int)e[c].x);   // SGPR row index
        v[c] = __uint_as_float(e[c].y);
        const float4* row = (const float4*)((const char*)wp + ((size_t)kk << 13));
        w[c] = row[j];                                          // saddr + j*16 load
    }
}

__device__ __forceinline__ void fma_chunk(const float* v, const float4* w,
                                          float& ar, float& az, float& a3) {
    #pragma unroll
    for (int c = 0; c < CH; ++c) {
        ar += v[c] * w[c].x;
        az += v[c] * w[c].y;
        a3 += v[c] * w[c].z;
    }
}

__device__ __forceinline__ void mac_list(const uint2* __restrict__ lst, int n,
                                         const float4* __restrict__ wp, int j,
                                         float& ar, float& az, float& a3) {
    const int nch = n / CH;          // even (n is a multiple of 2*CH)
    if (nch == 0) return;
    float vA[CH]; float4 wA[CH];
    float vB[CH]; float4 wB[CH];
    load_chunk(lst, 0, wp, j, vA, wA);
    if (nch > 1) load_chunk(lst, 1, wp, j, vB, wB);
    for (int ch = 0; ch < nch; ch += 2) {
        fma_chunk(vA, wA, ar, az, a3);
        if (ch + 2 < nch) load_chunk(lst, ch + 2, wp, j, vA, wA);
        if (ch + 1 < nch) fma_chunk(vB, wB, ar, az, a3);
        if (ch + 3 < nch) load_chunk(lst, ch + 3, wp, j, vB, wB);
    }
}

// ---- main persistent kernel: one 512-thread workgroup per batch element ----
__global__ __launch_bounds__(512, 2)
void dgru_fast(const float* __restrict__ x,
               const float4* __restrict__ wih0p,   // [6][512] float4
               const float4* __restrict__ whh0p,   // [512][512] float4
               const float4* __restrict__ wih1p,
               const float4* __restrict__ whh1p,
               const float* __restrict__ bih0, const float* __restrict__ bhh0,
               const float* __restrict__ bih1, const float* __restrict__ bhh1,
               const float* __restrict__ wfc,
               float* __restrict__ ws_fc) {        // [B][T][8 waves][2] partials
    __shared__ float s_x[2 * NT];                  // this batch's raw input (8 KB)
    __shared__ float s_dx0[8];
    __shared__ float s_xp0[8];
    __shared__ int   s_cnt[3][8];
    __shared__ uint2 s_listA[HID + 32];
    __shared__ uint2 s_listB[HID + 32];
    __shared__ uint2 s_listC[HID + 32];

    const int j    = threadIdx.x;
    const int lane = j & 63;
    const int wid  = j >> 6;
    const int b    = blockIdx.x;

    float h0 = 0.f, h0p = 0.f, xp1 = 0.f, h1 = 0.f, h1p = 0.f;
    float cr0 = bih0[j]       + bhh0[j];
    float cz0 = bih0[HID + j] + bhh0[HID + j];
    float cn0 = bih0[2*HID + j];
    float cnh0 = bhh0[2*HID + j];
    float cr1 = bih1[j]       + bhh1[j];
    float cz1 = bih1[HID + j] + bhh1[HID + j];
    float cn1 = bih1[2*HID + j];
    float cnh1 = bhh1[2*HID + j];

    if (j < 8) { s_xp0[j] = 0.f; s_dx0[j] = 0.f; }
    for (int i = j; i < 2 * NT; i += HID) s_x[i] = x[b * 2 * NT + i];

    const float wfc0 = wfc[j];
    const float wfc1 = wfc[HID + j];

    __syncthreads();

    for (int t = 0; t < NT; ++t) {
        // ---- layer0 deltas ----
        float d = h0 - h0p;
        if (fabsf(d) < THH) d = 0.f; else h0p = h0;
        unsigned long long mA = __ballot(d != 0.f);
        if (lane == 0) s_cnt[0][wid] = __popcll(mA);
        if (j < 6) {
            float iv = s_x[2 * t], qv = s_x[2 * t + 1];
            float amp = sqrtf(iv * iv + qv * qv);
            float f;
            if      (j == 0) f = iv;
            else if (j == 1) f = qv;
            else if (j == 2) f = amp;
            else if (j == 3) f = amp * amp * amp;
            else if (j == 4) f = qv / amp;
            else             f = iv / amp;
            float dx = f - s_xp0[j];
            if (fabsf(dx) < THX) dx = 0.f; else s_xp0[j] = f;
            s_dx0[j] = dx;
        }
        __syncthreads();                                   // S1
        int baseA = 0, nnzA = 0;
        #pragma unroll
        for (int w = 0; w < 8; ++w) {
            int c = s_cnt[0][w];
            baseA += (w < wid) ? c : 0;
            nnzA += c;
        }
        if (d != 0.f) {
            int pos = baseA + __popcll(mA & ((1ull << lane) - 1));
            s_listA[pos] = make_uint2((unsigned)j, __float_as_uint(d));
        }
        const int npadA = (nnzA + 31) & ~31;
        if (j < npadA - nnzA) s_listA[nnzA + j] = make_uint2(0u, 0u);
        __syncthreads();                                   // S2

        // ---- layer0 MAC + gates ----
        {
            float ar = cr0, az = cz0, an = cn0, anh = cnh0;
            #pragma unroll
            for (int f = 0; f < 6; ++f) {                  // dv==0 adds exact +0
                float dv = s_dx0[f];
                float4 w = wih0p[f * HID + j];
                ar += dv * w.x; az += dv * w.y; an += dv * w.z;
            }
            mac_list(s_listA, npadA, whh0p, j, ar, az, anh);
            cr0 = ar; cz0 = az; cn0 = an; cnh0 = anh;
            float r = 1.f / (1.f + expf(-ar));
            float z = 1.f / (1.f + expf(-az));
            float n = tanhf(an + r * anh);
            h0 = (1.f - z) * n + z * h0;
        }

        // ---- layer1 deltas ----
        float dxv = h0 - xp1;
        if (fabsf(dxv) < THX) dxv = 0.f; else xp1 = h0;
        float dhv = h1 - h1p;
        if (fabsf(dhv) < THH) dhv = 0.f; else h1p = h1;
        unsigned long long mB = __ballot(dxv != 0.f);
        unsigned long long mC = __ballot(dhv != 0.f);
        if (lane == 0) { s_cnt[1][wid] = __popcll(mB); s_cnt[2][wid] = __popcll(mC); }
        __syncthreads();                                   // S3
        int baseB = 0, nnzB = 0, baseC = 0, nnzC = 0;
        #pragma unroll
        for (int w = 0; w < 8; ++w) {
            int cb = s_cnt[1][w], cc = s_cnt[2][w];
            baseB += (w < wid) ? cb : 0;  nnzB += cb;
            baseC += (w < wid) ? cc : 0;  nnzC += cc;
        }
        if (dxv != 0.f) {
            int pos = baseB + __popcll(mB & ((1ull << lane) - 1));
            s_listB[pos] = make_uint2((unsigned)j, __float_as_uint(dxv));
        }
        if (dhv != 0.f) {
            int pos = baseC + __popcll(mC & ((1ull << lane) - 1));
            s_listC[pos] = make_uint2((unsigned)j, __float_as_uint(dhv));
        }
        const int npadB = (nnzB + 31) & ~31;
        const int npadC = (nnzC + 31) & ~31;
        if (j < npadB - nnzB) s_listB[nnzB + j] = make_uint2(0u, 0u);
        if (j < npadC - nnzC) s_listC[nnzC + j] = make_uint2(0u, 0u);
        __syncthreads();                                   // S4

        // ---- layer1 MAC + gates ----
        {
            float ar = cr1, az = cz1, an = cn1, anh = cnh1;
            mac_list(s_listB, npadB, wih1p, j, ar, az, an);
            mac_list(s_listC, npadC, whh1p, j, ar, az, anh);
            cr1 = ar; cz1 = az; cn1 = an; cnh1 = anh;
            float r = 1.f / (1.f + expf(-ar));
            float z = 1.f / (1.f + expf(-az));
            float n = tanhf(an + r * anh);
            h1 = (1.f - z) * n + z * h1;
        }

        // ---- FC head: per-wave partials, fire-and-forget store ----
        float p0 = h1 * wfc0, p1 = h1 * wfc1;
        #pragma unroll
        for (int off = 32; off > 0; off >>= 1) {
            p0 += __shfl_down(p0, off, 64);
            p1 += __shfl_down(p1, off, 64);
        }
        if (lane == 0) {
            float2* dst = (float2*)(ws_fc + ((size_t)(b * NT + t) * 8 + wid) * 2);
            *dst = make_float2(p0, p1);
        }
        // no barrier: next iteration's first reader of any LDS buffer is
        // separated from this iteration's writers by S1/S2 barriers.
    }
}

// ---- epilogue: deterministic ascending-wave FC reduction ----
__global__ void fc_reduce(const float* __restrict__ ws_fc,
                          const float* __restrict__ bfc,
                          float* __restrict__ out) {
    int idx = blockIdx.x * blockDim.x + threadIdx.x;   // (b*NT + t), 65536 total
    if (idx < NB * NT) {
        const float2* p = (const float2*)(ws_fc + (size_t)idx * 16);
        float o0 = bfc[0], o1 = bfc[1];
        #pragma unroll
        for (int w = 0; w < 8; ++w) { o0 += p[w].x; o1 += p[w].y; }
        out[idx * 2 + 0] = o0;
        out[idx * 2 + 1] = o1;
    }
}

// ---- safety-net fallback (ws too small): dense branchy loops, inline FC ----
__global__ __launch_bounds__(512)
void dgru_raw(const float* __restrict__ x,
              const float* __restrict__ wih0, const float* __restrict__ whh0,
              const float* __restrict__ wih1, const float* __restrict__ whh1,
              const float* __restrict__ bih0, const float* __restrict__ bhh0,
              const float* __restrict__ bih1, const float* __restrict__ bhh1,
              const float* __restrict__ wfc,  const float* __restrict__ bfc,
              float* __restrict__ out) {
    __shared__ float s_dx0[8];
    __shared__ float s_xp0[8];
    __shared__ float s_dh0[HID];
    __shared__ float s_dx1[HID];
    __shared__ float s_dh1[HID];
    __shared__ float s_part[16];

    const int j = threadIdx.x;
    const int b = blockIdx.x;
    float h0 = 0.f, h0p = 0.f, xp1 = 0.f, h1 = 0.f, h1p = 0.f;
    float cr0 = bih0[j] + bhh0[j];
    float cz0 = bih0[HID + j] + bhh0[HID + j];
    float cn0 = bih0[2*HID + j];
    float cnh0 = bhh0[2*HID + j];
    float cr1 = bih1[j] + bhh1[j];
    float cz1 = bih1[HID + j] + bhh1[HID + j];
    float cn1 = bih1[2*HID + j];
    float cnh1 = bhh1[2*HID + j];
    if (j < 8) { s_xp0[j] = 0.f; s_dx0[j] = 0.f; }
    const float wfc0 = wfc[j], wfc1 = wfc[HID + j];
    __syncthreads();

    for (int t = 0; t < NT; ++t) {
        float d = h0 - h0p;
        if (fabsf(d) < THH) d = 0.f; else h0p = h0;
        s_dh0[j] = d;
        if (j < 6) {
            float iv = x[(b * NT + t) * 2 + 0];
            float qv = x[(b * NT + t) * 2 + 1];
            float amp = sqrtf(iv * iv + qv * qv);
            float f;
            if      (j == 0) f = iv;
            else if (j == 1) f = qv;
            else if (j == 2) f = amp;
            else if (j == 3) f = amp * amp * amp;
            else if (j == 4) f = qv / amp;
            else             f = iv / amp;
            float dx = f - s_xp0[j];
            if (fabsf(dx) < THX) dx = 0.f; else s_xp0[j] = f;
            s_dx0[j] = dx;
        }
        __syncthreads();
        {
            float ar = cr0, az = cz0, an = cn0, anh = cnh0;
            #pragma unroll
            for (int f = 0; f < 6; ++f) {
                float dv = s_dx0[f];
                ar += dv * wih0[j * 6 + f];
                az += dv * wih0[(HID + j) * 6 + f];
                an += dv * wih0[(2*HID + j) * 6 + f];
            }
            for (int k = 0; k < HID; ++k) {
                float dv = s_dh0[k];
                if (dv != 0.f) {
                    ar  += dv * whh0[j * HID + k];
                    az  += dv * whh0[(HID + j) * HID + k];
                    anh += dv * whh0[(2*HID + j) * HID + k];
                }
            }
            cr0 = ar; cz0 = az; cn0 = an; cnh0 = anh;
            float r = 1.f / (1.f + expf(-ar));
            float z = 1.f / (1.f + expf(-az));
            float n = tanhf(an + r * anh);
            h0 = (1.f - z) * n + z * h0;
        }
        float dxv = h0 - xp1;
        if (fabsf(dxv) < THX) dxv = 0.f; else xp1 = h0;
        s_dx1[j] = dxv;
        float dhv = h1 - h1p;
        if (fabsf(dhv) < THH) dhv = 0.f; else h1p = h1;
        s_dh1[j] = dhv;
        __syncthreads();
        {
            float ar = cr1, az = cz1, an = cn1, anh = cnh1;
            for (int k = 0; k < HID; ++k) {
                float dv = s_dx1[k];
                if (dv != 0.f) {
                    ar += dv * wih1[j * HID + k];
                    az += dv * wih1[(HID + j) * HID + k];
                    an += dv * wih1[(2*HID + j) * HID + k];
                }
            }
            for (int k = 0; k < HID; ++k) {
                float dv = s_dh1[k];
                if (dv != 0.f) {
                    ar  += dv * whh1[j * HID + k];
                    az  += dv * whh1[(HID + j) * HID + k];
                    anh += dv * whh1[(2*HID + j) * HID + k];
                }
            }
            cr1 = ar; cz1 = az; cn1 = an; cnh1 = anh;
            float r = 1.f / (1.f + expf(-ar));
            float z = 1.f / (1.f + expf(-az));
            float n = tanhf(an + r * anh);
            h1 = (1.f - z) * n + z * h1;
        }
        float p0 = h1 * wfc0, p1 = h1 * wfc1;
        #pragma unroll
        for (int off = 32; off > 0; off >>= 1) {
            p0 += __shfl_down(p0, off, 64);
            p1 += __shfl_down(p1, off, 64);
        }
        if ((j & 63) == 0) { s_part[(j >> 6) * 2] = p0; s_part[(j >> 6) * 2 + 1] = p1; }
        __syncthreads();
        if (j == 0) {
            float o0 = bfc[0], o1 = bfc[1];
            #pragma unroll
            for (int w = 0; w < 8; ++w) { o0 += s_part[w * 2]; o1 += s_part[w * 2 + 1]; }
            out[(b * NT + t) * 2 + 0] = o0;
            out[(b * NT + t) * 2 + 1] = o1;
        }
    }
}

extern "C" void kernel_launch(void* const* d_in, const int* in_sizes, int n_in,
                              void* d_out, int out_size, void* d_ws, size_t ws_size,
                              hipStream_t stream) {
    const float* x    = (const float*)d_in[0];
    // d_in[1] = h_0 : reference zero-inits h, input unused
    const float* wih0 = (const float*)d_in[2];
    const float* whh0 = (const float*)d_in[3];
    const float* bih0 = (const float*)d_in[4];
    const float* bhh0 = (const float*)d_in[5];
    const float* wih1 = (const float*)d_in[6];
    const float* whh1 = (const float*)d_in[7];
    const float* bih1 = (const float*)d_in[8];
    const float* bhh1 = (const float*)d_in[9];
    const float* wfc  = (const float*)d_in[10];
    const float* bfc  = (const float*)d_in[11];
    float* out = (float*)d_out;

    const size_t MAT4  = (size_t)HID * 2048 * sizeof(float);     // 4 MiB per packed matrix
    const size_t o_ih0 = 0;                                       // 48 KiB
    const size_t o_hh0 = 6 * 2048 * sizeof(float);
    const size_t o_ih1 = o_hh0 + MAT4;
    const size_t o_hh1 = o_ih1 + MAT4;
    const size_t o_fc  = o_hh1 + MAT4;
    const size_t FCB   = (size_t)NB * NT * 8 * 2 * sizeof(float); // 4 MiB partials
    const size_t need  = o_fc + FCB;                              // ~16.3 MiB

    if (ws_size >= need) {
        float* wt_ih0 = (float*)((char*)d_ws + o_ih0);
        float* wt_hh0 = (float*)((char*)d_ws + o_hh0);
        float* wt_ih1 = (float*)((char*)d_ws + o_ih1);
        float* wt_hh1 = (float*)((char*)d_ws + o_hh1);
        float* ws_fc  = (float*)((char*)d_ws + o_fc);
        pack_ih0<<<(6 * HID + 255) / 256, 256, 0, stream>>>(wih0, wt_ih0);
        pack_h4<<<(HID * HID + 255) / 256, 256, 0, stream>>>(whh0, wt_hh0);
        pack_h4<<<(HID * HID + 255) / 256, 256, 0, stream>>>(wih1, wt_ih1);
        pack_h4<<<(HID * HID + 255) / 256, 256, 0, stream>>>(whh1, wt_hh1);
        dgru_fast<<<NB, HID, 0, stream>>>(x,
                                          (const float4*)wt_ih0, (const float4*)wt_hh0,
                                          (const float4*)wt_ih1, (const float4*)wt_hh1,
                                          bih0, bhh0, bih1, bhh1, wfc, ws_fc);
        fc_reduce<<<(NB * NT + 255) / 256, 256, 0, stream>>>(ws_fc, bfc, out);
    } else {
        dgru_raw<<<NB, HID, 0, stream>>>(x, wih0, whh0, wih1, whh1,
                                         bih0, bhh0, bih1, bhh1, wfc, bfc, out);
    }
}

// Round 5
// 133237.061 us; speedup vs baseline: 1.0542x; 1.0542x over previous
//
#include <hip/hip_runtime.h>

#define HID 512
#define NB  64
#define NT  1024
#define THX 0.1f
#define THH 0.05f
#define CH  16   // entries per pipeline chunk, 2 chunks in flight

// ---- prep: pack W_ih_l0 [1536][6] f32 -> [6][512]{r,z,n} float3 ----
__global__ void pack_ih0(const float* __restrict__ src, float* __restrict__ dst) {
    int idx = blockIdx.x * blockDim.x + threadIdx.x;
    if (idx < 6 * HID) {
        int f = idx / HID, j = idx % HID;
        dst[f * 1536 + j * 3 + 0] = src[(0 * HID + j) * 6 + f];
        dst[f * 1536 + j * 3 + 1] = src[(1 * HID + j) * 6 + f];
        dst[f * 1536 + j * 3 + 2] = src[(2 * HID + j) * 6 + f];
    }
}

// ---- prep: pack a [1536][512] f32 matrix -> [512(k)][512(j)]{r,z,n} float3 ----
// row k at byte offset k*6144; thread j loads 12 contiguous bytes.
__global__ void pack_h3(const float* __restrict__ src, float* __restrict__ dst) {
    int idx = blockIdx.x * blockDim.x + threadIdx.x;
    if (idx < HID * HID) {
        int k = idx / HID, j = idx % HID;
        dst[k * 1536 + j * 3 + 0] = src[(0 * HID + j) * HID + k];
        dst[k * 1536 + j * 3 + 1] = src[(1 * HID + j) * HID + k];
        dst[k * 1536 + j * 3 + 2] = src[(2 * HID + j) * HID + k];
    }
}

// ---- pipelined sparse MAC ----
// lst: compacted (k, val), zero-padded to n (multiple of 32; pads add exact +0).
// wp: packed float3 matrix, row k at byte offset k*6144.
__device__ __forceinline__ void load_chunk(const uint2* __restrict__ lst, int ch,
                                           const float* __restrict__ wp, int j,
                                           float* v, float3* w) {
    uint2 e[CH];
    #pragma unroll
    for (int c = 0; c < CH; ++c) e[c] = lst[ch * CH + c];      // uniform LDS reads
    #pragma unroll
    for (int c = 0; c < CH; ++c) {
        int kk = __builtin_amdgcn_readfirstlane((int)e[c].x);  // SGPR row index
        v[c] = __uint_as_float(e[c].y);
        const float3* row = (const float3*)(wp + (size_t)kk * 1536);
        w[c] = row[j];                                          // 12B coalesced load
    }
}

__device__ __forceinline__ void fma_chunk(const float* v, const float3* w,
                                          float& ar, float& az, float& a3) {
    #pragma unroll
    for (int c = 0; c < CH; ++c) {
        ar += v[c] * w[c].x;
        az += v[c] * w[c].y;
        a3 += v[c] * w[c].z;
    }
}

__device__ __forceinline__ void mac_list(const uint2* __restrict__ lst, int n,
                                         const float* __restrict__ wp, int j,
                                         float& ar, float& az, float& a3) {
    const int nch = n / CH;          // even (n is a multiple of 2*CH)
    if (nch == 0) return;
    float vA[CH]; float3 wA[CH];
    float vB[CH]; float3 wB[CH];
    load_chunk(lst, 0, wp, j, vA, wA);
    if (nch > 1) load_chunk(lst, 1, wp, j, vB, wB);
    for (int ch = 0; ch < nch; ch += 2) {
        fma_chunk(vA, wA, ar, az, a3);
        if (ch + 2 < nch) load_chunk(lst, ch + 2, wp, j, vA, wA);
        if (ch + 1 < nch) fma_chunk(vB, wB, ar, az, a3);
        if (ch + 3 < nch) load_chunk(lst, ch + 3, wp, j, vB, wB);
    }
}

// ---- main persistent kernel: one 512-thread workgroup per batch element ----
// launch_bounds(512, 1): grid=64 on 256 CUs -> 1 WG/CU regardless; allow 256 VGPRs
// so the depth-2 CH=16 pipeline buffers live in registers (round 4 spilled at 128).
__global__ __launch_bounds__(512, 1)
void dgru_fast(const float* __restrict__ x,
               const float* __restrict__ wih0p,   // [6][512] float3
               const float* __restrict__ whh0p,   // [512][512] float3
               const float* __restrict__ wih1p,
               const float* __restrict__ whh1p,
               const float* __restrict__ bih0, const float* __restrict__ bhh0,
               const float* __restrict__ bih1, const float* __restrict__ bhh1,
               const float* __restrict__ wfc,
               float* __restrict__ ws_fc) {       // [B][T][8 waves][2] partials
    __shared__ float s_x[2 * NT];                 // this batch's raw input (8 KB)
    __shared__ float s_dx0[8];
    __shared__ float s_xp0[8];
    __shared__ int   s_cnt[3][8];
    __shared__ uint2 s_listA[HID + 32];
    __shared__ uint2 s_listB[HID + 32];
    __shared__ uint2 s_listC[HID + 32];

    const int j    = threadIdx.x;
    const int lane = j & 63;
    const int wid  = j >> 6;
    const int b    = blockIdx.x;

    float h0 = 0.f, h0p = 0.f, xp1 = 0.f, h1 = 0.f, h1p = 0.f;
    float cr0 = bih0[j]       + bhh0[j];
    float cz0 = bih0[HID + j] + bhh0[HID + j];
    float cn0 = bih0[2*HID + j];
    float cnh0 = bhh0[2*HID + j];
    float cr1 = bih1[j]       + bhh1[j];
    float cz1 = bih1[HID + j] + bhh1[HID + j];
    float cn1 = bih1[2*HID + j];
    float cnh1 = bhh1[2*HID + j];

    if (j < 8) { s_xp0[j] = 0.f; s_dx0[j] = 0.f; }
    for (int i = j; i < 2 * NT; i += HID) s_x[i] = x[b * 2 * NT + i];

    const float wfc0 = wfc[j];
    const float wfc1 = wfc[HID + j];

    __syncthreads();

    for (int t = 0; t < NT; ++t) {
        // ---- layer0 deltas ----
        float d = h0 - h0p;
        if (fabsf(d) < THH) d = 0.f; else h0p = h0;
        unsigned long long mA = __ballot(d != 0.f);
        if (lane == 0) s_cnt[0][wid] = __popcll(mA);
        if (j < 6) {
            float iv = s_x[2 * t], qv = s_x[2 * t + 1];
            float amp = sqrtf(iv * iv + qv * qv);
            float f;
            if      (j == 0) f = iv;
            else if (j == 1) f = qv;
            else if (j == 2) f = amp;
            else if (j == 3) f = amp * amp * amp;
            else if (j == 4) f = qv / amp;
            else             f = iv / amp;
            float dx = f - s_xp0[j];
            if (fabsf(dx) < THX) dx = 0.f; else s_xp0[j] = f;
            s_dx0[j] = dx;
        }
        __syncthreads();                                   // S1
        int baseA = 0, nnzA = 0;
        #pragma unroll
        for (int w = 0; w < 8; ++w) {
            int c = s_cnt[0][w];
            baseA += (w < wid) ? c : 0;
            nnzA += c;
        }
        if (d != 0.f) {
            int pos = baseA + __popcll(mA & ((1ull << lane) - 1));
            s_listA[pos] = make_uint2((unsigned)j, __float_as_uint(d));
        }
        const int npadA = (nnzA + 31) & ~31;
        if (j < npadA - nnzA) s_listA[nnzA + j] = make_uint2(0u, 0u);
        __syncthreads();                                   // S2

        // ---- layer0 MAC + gates ----
        {
            float ar = cr0, az = cz0, an = cn0, anh = cnh0;
            #pragma unroll
            for (int f = 0; f < 6; ++f) {                  // dv==0 adds exact +0
                float dv = s_dx0[f];
                const float3* row = (const float3*)(wih0p + f * 1536);
                float3 w = row[j];
                ar += dv * w.x; az += dv * w.y; an += dv * w.z;
            }
            mac_list(s_listA, npadA, whh0p, j, ar, az, anh);
            cr0 = ar; cz0 = az; cn0 = an; cnh0 = anh;
            float r = 1.f / (1.f + expf(-ar));
            float z = 1.f / (1.f + expf(-az));
            float n = tanhf(an + r * anh);
            h0 = (1.f - z) * n + z * h0;
        }

        // ---- layer1 deltas ----
        float dxv = h0 - xp1;
        if (fabsf(dxv) < THX) dxv = 0.f; else xp1 = h0;
        float dhv = h1 - h1p;
        if (fabsf(dhv) < THH) dhv = 0.f; else h1p = h1;
        unsigned long long mB = __ballot(dxv != 0.f);
        unsigned long long mC = __ballot(dhv != 0.f);
        if (lane == 0) { s_cnt[1][wid] = __popcll(mB); s_cnt[2][wid] = __popcll(mC); }
        __syncthreads();                                   // S3
        int baseB = 0, nnzB = 0, baseC = 0, nnzC = 0;
        #pragma unroll
        for (int w = 0; w < 8; ++w) {
            int cb = s_cnt[1][w], cc = s_cnt[2][w];
            baseB += (w < wid) ? cb : 0;  nnzB += cb;
            baseC += (w < wid) ? cc : 0;  nnzC += cc;
        }
        if (dxv != 0.f) {
            int pos = baseB + __popcll(mB & ((1ull << lane) - 1));
            s_listB[pos] = make_uint2((unsigned)j, __float_as_uint(dxv));
        }
        if (dhv != 0.f) {
            int pos = baseC + __popcll(mC & ((1ull << lane) - 1));
            s_listC[pos] = make_uint2((unsigned)j, __float_as_uint(dhv));
        }
        const int npadB = (nnzB + 31) & ~31;
        const int npadC = (nnzC + 31) & ~31;
        if (j < npadB - nnzB) s_listB[nnzB + j] = make_uint2(0u, 0u);
        if (j < npadC - nnzC) s_listC[nnzC + j] = make_uint2(0u, 0u);
        __syncthreads();                                   // S4

        // ---- layer1 MAC + gates ----
        {
            float ar = cr1, az = cz1, an = cn1, anh = cnh1;
            mac_list(s_listB, npadB, wih1p, j, ar, az, an);
            mac_list(s_listC, npadC, whh1p, j, ar, az, anh);
            cr1 = ar; cz1 = az; cn1 = an; cnh1 = anh;
            float r = 1.f / (1.f + expf(-ar));
            float z = 1.f / (1.f + expf(-az));
            float n = tanhf(an + r * anh);
            h1 = (1.f - z) * n + z * h1;
        }

        // ---- FC head: per-wave partials, fire-and-forget store ----
        float p0 = h1 * wfc0, p1 = h1 * wfc1;
        #pragma unroll
        for (int off = 32; off > 0; off >>= 1) {
            p0 += __shfl_down(p0, off, 64);
            p1 += __shfl_down(p1, off, 64);
        }
        if (lane == 0) {
            float2* dst = (float2*)(ws_fc + ((size_t)(b * NT + t) * 8 + wid) * 2);
            *dst = make_float2(p0, p1);
        }
    }
}

// ---- epilogue: deterministic ascending-wave FC reduction ----
__global__ void fc_reduce(const float* __restrict__ ws_fc,
                          const float* __restrict__ bfc,
                          float* __restrict__ out) {
    int idx = blockIdx.x * blockDim.x + threadIdx.x;   // (b*NT + t)
    if (idx < NB * NT) {
        const float2* p = (const float2*)(ws_fc + (size_t)idx * 16);
        float o0 = bfc[0], o1 = bfc[1];
        #pragma unroll
        for (int w = 0; w < 8; ++w) { o0 += p[w].x; o1 += p[w].y; }
        out[idx * 2 + 0] = o0;
        out[idx * 2 + 1] = o1;
    }
}

// ---- safety-net fallback (ws too small): dense branchy loops, inline FC ----
__global__ __launch_bounds__(512)
void dgru_raw(const float* __restrict__ x,
              const float* __restrict__ wih0, const float* __restrict__ whh0,
              const float* __restrict__ wih1, const float* __restrict__ whh1,
              const float* __restrict__ bih0, const float* __restrict__ bhh0,
              const float* __restrict__ bih1, const float* __restrict__ bhh1,
              const float* __restrict__ wfc,  const float* __restrict__ bfc,
              float* __restrict__ out) {
    __shared__ float s_dx0[8];
    __shared__ float s_xp0[8];
    __shared__ float s_dh0[HID];
    __shared__ float s_dx1[HID];
    __shared__ float s_dh1[HID];
    __shared__ float s_part[16];

    const int j = threadIdx.x;
    const int b = blockIdx.x;
    float h0 = 0.f, h0p = 0.f, xp1 = 0.f, h1 = 0.f, h1p = 0.f;
    float cr0 = bih0[j] + bhh0[j];
    float cz0 = bih0[HID + j] + bhh0[HID + j];
    float cn0 = bih0[2*HID + j];
    float cnh0 = bhh0[2*HID + j];
    float cr1 = bih1[j] + bhh1[j];
    float cz1 = bih1[HID + j] + bhh1[HID + j];
    float cn1 = bih1[2*HID + j];
    float cnh1 = bhh1[2*HID + j];
    if (j < 8) { s_xp0[j] = 0.f; s_dx0[j] = 0.f; }
    const float wfc0 = wfc[j], wfc1 = wfc[HID + j];
    __syncthreads();

    for (int t = 0; t < NT; ++t) {
        float d = h0 - h0p;
        if (fabsf(d) < THH) d = 0.f; else h0p = h0;
        s_dh0[j] = d;
        if (j < 6) {
            float iv = x[(b * NT + t) * 2 + 0];
            float qv = x[(b * NT + t) * 2 + 1];
            float amp = sqrtf(iv * iv + qv * qv);
            float f;
            if      (j == 0) f = iv;
            else if (j == 1) f = qv;
            else if (j == 2) f = amp;
            else if (j == 3) f = amp * amp * amp;
            else if (j == 4) f = qv / amp;
            else             f = iv / amp;
            float dx = f - s_xp0[j];
            if (fabsf(dx) < THX) dx = 0.f; else s_xp0[j] = f;
            s_dx0[j] = dx;
        }
        __syncthreads();
        {
            float ar = cr0, az = cz0, an = cn0, anh = cnh0;
            #pragma unroll
            for (int f = 0; f < 6; ++f) {
                float dv = s_dx0[f];
                ar += dv * wih0[j * 6 + f];
                az += dv * wih0[(HID + j) * 6 + f];
                an += dv * wih0[(2*HID + j) * 6 + f];
            }
            for (int k = 0; k < HID; ++k) {
                float dv = s_dh0[k];
                if (dv != 0.f) {
                    ar  += dv * whh0[j * HID + k];
                    az  += dv * whh0[(HID + j) * HID + k];
                    anh += dv * whh0[(2*HID + j) * HID + k];
                }
            }
            cr0 = ar; cz0 = az; cn0 = an; cnh0 = anh;
            float r = 1.f / (1.f + expf(-ar));
            float z = 1.f / (1.f + expf(-az));
            float n = tanhf(an + r * anh);
            h0 = (1.f - z) * n + z * h0;
        }
        float dxv = h0 - xp1;
        if (fabsf(dxv) < THX) dxv = 0.f; else xp1 = h0;
        s_dx1[j] = dxv;
        float dhv = h1 - h1p;
        if (fabsf(dhv) < THH) dhv = 0.f; else h1p = h1;
        s_dh1[j] = dhv;
        __syncthreads();
        {
            float ar = cr1, az = cz1, an = cn1, anh = cnh1;
            for (int k = 0; k < HID; ++k) {
                float dv = s_dx1[k];
                if (dv != 0.f) {
                    ar += dv * wih1[j * HID + k];
                    az += dv * wih1[(HID + j) * HID + k];
                    an += dv * wih1[(2*HID + j) * HID + k];
                }
            }
            for (int k = 0; k < HID; ++k) {
                float dv = s_dh1[k];
                if (dv != 0.f) {
                    ar  += dv * whh1[j * HID + k];
                    az  += dv * whh1[(HID + j) * HID + k];
                    anh += dv * whh1[(2*HID + j) * HID + k];
                }
            }
            cr1 = ar; cz1 = az; cn1 = an; cnh1 = anh;
            float r = 1.f / (1.f + expf(-ar));
            float z = 1.f / (1.f + expf(-az));
            float n = tanhf(an + r * anh);
            h1 = (1.f - z) * n + z * h1;
        }
        float p0 = h1 * wfc0, p1 = h1 * wfc1;
        #pragma unroll
        for (int off = 32; off > 0; off >>= 1) {
            p0 += __shfl_down(p0, off, 64);
            p1 += __shfl_down(p1, off, 64);
        }
        if ((j & 63) == 0) { s_part[(j >> 6) * 2] = p0; s_part[(j >> 6) * 2 + 1] = p1; }
        __syncthreads();
        if (j == 0) {
            float o0 = bfc[0], o1 = bfc[1];
            #pragma unroll
            for (int w = 0; w < 8; ++w) { o0 += s_part[w * 2]; o1 += s_part[w * 2 + 1]; }
            out[(b * NT + t) * 2 + 0] = o0;
            out[(b * NT + t) * 2 + 1] = o1;
        }
    }
}

extern "C" void kernel_launch(void* const* d_in, const int* in_sizes, int n_in,
                              void* d_out, int out_size, void* d_ws, size_t ws_size,
                              hipStream_t stream) {
    const float* x    = (const float*)d_in[0];
    // d_in[1] = h_0 : reference zero-inits h, input unused
    const float* wih0 = (const float*)d_in[2];
    const float* whh0 = (const float*)d_in[3];
    const float* bih0 = (const float*)d_in[4];
    const float* bhh0 = (const float*)d_in[5];
    const float* wih1 = (const float*)d_in[6];
    const float* whh1 = (const float*)d_in[7];
    const float* bih1 = (const float*)d_in[8];
    const float* bhh1 = (const float*)d_in[9];
    const float* wfc  = (const float*)d_in[10];
    const float* bfc  = (const float*)d_in[11];
    float* out = (float*)d_out;

    const size_t MAT3  = (size_t)HID * 1536 * sizeof(float);      // 3 MiB per packed matrix
    const size_t o_ih0 = 0;                                        // 6*1536*4 = 36 KiB
    const size_t o_hh0 = 6 * 1536 * sizeof(float);
    const size_t o_ih1 = o_hh0 + MAT3;
    const size_t o_hh1 = o_ih1 + MAT3;
    const size_t o_fc  = o_hh1 + MAT3;
    const size_t FCB   = (size_t)NB * NT * 8 * 2 * sizeof(float);  // 4 MiB partials
    const size_t need  = o_fc + FCB;                               // ~13 MiB

    if (ws_size >= need) {
        float* wt_ih0 = (float*)((char*)d_ws + o_ih0);
        float* wt_hh0 = (float*)((char*)d_ws + o_hh0);
        float* wt_ih1 = (float*)((char*)d_ws + o_ih1);
        float* wt_hh1 = (float*)((char*)d_ws + o_hh1);
        float* ws_fc  = (float*)((char*)d_ws + o_fc);
        pack_ih0<<<(6 * HID + 255) / 256, 256, 0, stream>>>(wih0, wt_ih0);
        pack_h3<<<(HID * HID + 255) / 256, 256, 0, stream>>>(whh0, wt_hh0);
        pack_h3<<<(HID * HID + 255) / 256, 256, 0, stream>>>(wih1, wt_ih1);
        pack_h3<<<(HID * HID + 255) / 256, 256, 0, stream>>>(whh1, wt_hh1);
        dgru_fast<<<NB, HID, 0, stream>>>(x, wt_ih0, wt_hh0, wt_ih1, wt_hh1,
                                          bih0, bhh0, bih1, bhh1, wfc, ws_fc);
        fc_reduce<<<(NB * NT + 255) / 256, 256, 0, stream>>>(ws_fc, bfc, out);
    } else {
        dgru_raw<<<NB, HID, 0, stream>>>(x, wih0, whh0, wih1, whh1,
                                         bih0, bhh0, bih1, bhh1, wfc, bfc, out);
    }
}

// Round 6
// 72429.346 us; speedup vs baseline: 1.9392x; 1.8395x over previous
//
#include <hip/hip_runtime.h>

#define HID 512
#define NB  64
#define NT  1024
#define THX 0.1f
#define THH 0.05f

// ---- prep: pack W_ih_l0 [1536][6] f32 -> [6][512]{r,z,n} float3 ----
__global__ void pack_ih0(const float* __restrict__ src, float* __restrict__ dst) {
    int idx = blockIdx.x * blockDim.x + threadIdx.x;
    if (idx < 6 * HID) {
        int f = idx / HID, j = idx % HID;
        dst[f * 1536 + j * 3 + 0] = src[(0 * HID + j) * 6 + f];
        dst[f * 1536 + j * 3 + 1] = src[(1 * HID + j) * 6 + f];
        dst[f * 1536 + j * 3 + 2] = src[(2 * HID + j) * 6 + f];
    }
}

// ---- prep: pack a [1536][512] f32 matrix -> [512(k)][512(j)]{r,z,n} float3 ----
__global__ void pack_h3(const float* __restrict__ src, float* __restrict__ dst) {
    int idx = blockIdx.x * blockDim.x + threadIdx.x;
    if (idx < HID * HID) {
        int k = idx / HID, j = idx % HID;
        dst[k * 1536 + j * 3 + 0] = src[(0 * HID + j) * HID + k];
        dst[k * 1536 + j * 3 + 1] = src[(1 * HID + j) * HID + k];
        dst[k * 1536 + j * 3 + 2] = src[(2 * HID + j) * HID + k];
    }
}

// ---- round-3-style sparse MAC: compacted (k,val) list, float3 rows ----
// n is a multiple of 32; pad entries are (k=0, v=0) -> exact +0.0 adds.
__device__ __forceinline__ void mac3(const uint2* __restrict__ lst, int n,
                                     const float* __restrict__ wp, int j,
                                     float& a0, float& a1, float& a2) {
    #pragma unroll 8
    for (int i = 0; i < n; ++i) {
        uint2 e = lst[i];                      // uniform LDS read (broadcast)
        float dv = __uint_as_float(e.y);
        const float3* row = (const float3*)(wp + (size_t)e.x * 1536);
        float3 w = row[j];                     // 12B coalesced load
        a0 += dv * w.x; a1 += dv * w.y; a2 += dv * w.z;
    }
}

// ---- main kernel: 1024 threads/WG, 2-stage layer pipeline ----
// group A (tid 0..511):   layer 0 at step t     (owns h0, xp0, xp1, L0 carries)
// group B (tid 512..1023): layer 1 at step t-1  (owns h1, L1 carries, FC)
__global__ __launch_bounds__(1024)
void dgru_pipe(const float* __restrict__ x,
               const float* __restrict__ wih0p,   // [6][512] float3
               const float* __restrict__ whh0p,   // [512][512] float3
               const float* __restrict__ wih1p,
               const float* __restrict__ whh1p,
               const float* __restrict__ bih0, const float* __restrict__ bhh0,
               const float* __restrict__ bih1, const float* __restrict__ bhh1,
               const float* __restrict__ wfc,
               float* __restrict__ ws_fc) {       // [B][T][8 waves][2] partials
    __shared__ float s_x[2 * NT];                 // 8 KB raw input
    __shared__ float s_dx0[8];
    __shared__ float s_xp0[8];
    __shared__ int   s_cntA[8], s_cntB[8], s_cntC[8];
    __shared__ uint2 s_listA[HID + 32];           // L0 dh list   (A-internal)
    __shared__ uint2 s_listB[2][HID + 32];        // L1 dx list   (A->B, dbuf)
    __shared__ uint2 s_listC[HID + 32];           // L1 dh list   (B-internal)

    const int tid  = threadIdx.x;
    const int grp  = tid >> 9;          // 0 = A (layer0), 1 = B (layer1)
    const int j    = tid & (HID - 1);
    const int lane = tid & 63;
    const int gw   = (tid >> 6) & 7;    // wave index within group
    const int b    = blockIdx.x;

    // group A state
    float h0 = 0.f, h0p = 0.f, xp1 = 0.f;
    float cr0 = 0.f, cz0 = 0.f, cn0 = 0.f, cnh0 = 0.f;
    // group B state
    float h1 = 0.f, h1p = 0.f;
    float cr1 = 0.f, cz1 = 0.f, cn1 = 0.f, cnh1 = 0.f;
    float wfc0 = 0.f, wfc1 = 0.f;

    if (grp == 0) {
        cr0  = bih0[j]       + bhh0[j];
        cz0  = bih0[HID + j] + bhh0[HID + j];
        cn0  = bih0[2*HID + j];
        cnh0 = bhh0[2*HID + j];
    } else {
        cr1  = bih1[j]       + bhh1[j];
        cz1  = bih1[HID + j] + bhh1[HID + j];
        cn1  = bih1[2*HID + j];
        cnh1 = bhh1[2*HID + j];
        wfc0 = wfc[j];
        wfc1 = wfc[HID + j];
    }
    if (tid < 8) { s_xp0[tid] = 0.f; s_dx0[tid] = 0.f; }
    for (int i = tid; i < 2 * NT; i += 1024) s_x[i] = x[b * 2 * NT + i];
    __syncthreads();

    for (int t = 0; t < NT; ++t) {
        // ===== seg1: A computes dh0 + input features, publishes counts =====
        float dA = 0.f; unsigned long long mA = 0;
        if (grp == 0) {
            dA = h0 - h0p;
            if (fabsf(dA) < THH) dA = 0.f; else h0p = h0;
            mA = __ballot(dA != 0.f);
            if (lane == 0) s_cntA[gw] = __popcll(mA);
            if (tid < 6) {
                float iv = s_x[2 * t], qv = s_x[2 * t + 1];
                float amp = sqrtf(iv * iv + qv * qv);
                float f;
                if      (tid == 0) f = iv;
                else if (tid == 1) f = qv;
                else if (tid == 2) f = amp;
                else if (tid == 3) f = amp * amp * amp;
                else if (tid == 4) f = qv / amp;
                else               f = iv / amp;
                float dx = f - s_xp0[tid];
                if (fabsf(dx) < THX) dx = 0.f; else s_xp0[tid] = f;
                s_dx0[tid] = dx;
            }
        }
        __syncthreads();                                       // BAR1
        // ===== seg2: A scatters listA ======================================
        int npadA = 0;
        if (grp == 0) {
            int baseA = 0, nnzA = 0;
            #pragma unroll
            for (int w = 0; w < 8; ++w) {
                int c = s_cntA[w];
                baseA += (w < gw) ? c : 0;
                nnzA += c;
            }
            if (dA != 0.f) {
                int pos = baseA + __popcll(mA & ((1ull << lane) - 1));
                s_listA[pos] = make_uint2((unsigned)j, __float_as_uint(dA));
            }
            npadA = (nnzA + 31) & ~31;
            if (j < npadA - nnzA) s_listA[nnzA + j] = make_uint2(0u, 0u);
        }
        __syncthreads();                                       // BAR2
        // ===== seg3: A: L0 MAC+gates ||| B: L1(t-1) MAC+gates+FC ===========
        float dB = 0.f; unsigned long long mB = 0;   // A's dx1 delta
        float dC = 0.f; unsigned long long mC = 0;   // B's dh1 delta
        if (grp == 0) {
            float ar = cr0, az = cz0, an = cn0, anh = cnh0;
            #pragma unroll
            for (int f = 0; f < 6; ++f) {            // dv==0 adds exact +0
                float dv = s_dx0[f];
                const float3* row = (const float3*)(wih0p + f * 1536);
                float3 w = row[j];
                ar += dv * w.x; az += dv * w.y; an += dv * w.z;
            }
            mac3(s_listA, npadA, whh0p, j, ar, az, anh);
            cr0 = ar; cz0 = az; cn0 = an; cnh0 = anh;
            float r = 1.f / (1.f + expf(-ar));
            float z = 1.f / (1.f + expf(-az));
            float n = tanhf(an + r * anh);
            h0 = (1.f - z) * n + z * h0;
            dB = h0 - xp1;                           // dx1 for L1 step t
            if (fabsf(dB) < THX) dB = 0.f; else xp1 = h0;
            mB = __ballot(dB != 0.f);
            if (lane == 0) s_cntB[gw] = __popcll(mB);
        } else {
            if (t > 0) {
                float ar = cr1, az = cz1, an = cn1, anh = cnh1;
                int nB = 0, nC = 0;
                #pragma unroll
                for (int w = 0; w < 8; ++w) { nB += s_cntB[w]; nC += s_cntC[w]; }
                nB = (nB + 31) & ~31;
                nC = (nC + 31) & ~31;
                mac3(s_listB[(t - 1) & 1], nB, wih1p, j, ar, az, an);
                mac3(s_listC, nC, whh1p, j, ar, az, anh);
                cr1 = ar; cz1 = az; cn1 = an; cnh1 = anh;
                float r = 1.f / (1.f + expf(-ar));
                float z = 1.f / (1.f + expf(-az));
                float n = tanhf(an + r * anh);
                h1 = (1.f - z) * n + z * h1;
                float p0 = h1 * wfc0, p1 = h1 * wfc1;
                #pragma unroll
                for (int off = 32; off > 0; off >>= 1) {
                    p0 += __shfl_down(p0, off, 64);
                    p1 += __shfl_down(p1, off, 64);
                }
                if (lane == 0) {
                    float2* dst = (float2*)(ws_fc + ((size_t)(b * NT + (t - 1)) * 8 + gw) * 2);
                    *dst = make_float2(p0, p1);
                }
            }
            dC = h1 - h1p;                           // dh1 for L1 step t
            if (fabsf(dC) < THH) dC = 0.f; else h1p = h1;
            mC = __ballot(dC != 0.f);
            if (lane == 0) s_cntC[gw] = __popcll(mC);
        }
        __syncthreads();                                       // BAR3
        // ===== seg4: scatter listB (A) and listC (B) =======================
        if (grp == 0) {
            int baseB = 0, nnzB = 0;
            #pragma unroll
            for (int w = 0; w < 8; ++w) {
                int c = s_cntB[w];
                baseB += (w < gw) ? c : 0;
                nnzB += c;
            }
            if (dB != 0.f) {
                int pos = baseB + __popcll(mB & ((1ull << lane) - 1));
                s_listB[t & 1][pos] = make_uint2((unsigned)j, __float_as_uint(dB));
            }
            int npadB = (nnzB + 31) & ~31;
            if (j < npadB - nnzB) s_listB[t & 1][nnzB + j] = make_uint2(0u, 0u);
        } else {
            int baseC = 0, nnzC = 0;
            #pragma unroll
            for (int w = 0; w < 8; ++w) {
                int c = s_cntC[w];
                baseC += (w < gw) ? c : 0;
                nnzC += c;
            }
            if (dC != 0.f) {
                int pos = baseC + __popcll(mC & ((1ull << lane) - 1));
                s_listC[pos] = make_uint2((unsigned)j, __float_as_uint(dC));
            }
            int npadC = (nnzC + 31) & ~31;
            if (j < npadC - nnzC) s_listC[nnzC + j] = make_uint2(0u, 0u);
        }
        __syncthreads();                                       // BAR4
    }

    // ===== epilogue: B runs L1 for step NT-1 ===============================
    if (grp == 1) {
        float ar = cr1, az = cz1, an = cn1, anh = cnh1;
        int nB = 0, nC = 0;
        #pragma unroll
        for (int w = 0; w < 8; ++w) { nB += s_cntB[w]; nC += s_cntC[w]; }
        nB = (nB + 31) & ~31;
        nC = (nC + 31) & ~31;
        mac3(s_listB[(NT - 1) & 1], nB, wih1p, j, ar, az, an);
        mac3(s_listC, nC, whh1p, j, ar, az, anh);
        float r = 1.f / (1.f + expf(-ar));
        float z = 1.f / (1.f + expf(-az));
        float n = tanhf(an + r * anh);
        h1 = (1.f - z) * n + z * h1;
        float p0 = h1 * wfc0, p1 = h1 * wfc1;
        #pragma unroll
        for (int off = 32; off > 0; off >>= 1) {
            p0 += __shfl_down(p0, off, 64);
            p1 += __shfl_down(p1, off, 64);
        }
        if (lane == 0) {
            float2* dst = (float2*)(ws_fc + ((size_t)(b * NT + (NT - 1)) * 8 + gw) * 2);
            *dst = make_float2(p0, p1);
        }
    }
}

// ---- epilogue: deterministic ascending-wave FC reduction ----
__global__ void fc_reduce(const float* __restrict__ ws_fc,
                          const float* __restrict__ bfc,
                          float* __restrict__ out) {
    int idx = blockIdx.x * blockDim.x + threadIdx.x;   // (b*NT + t)
    if (idx < NB * NT) {
        const float2* p = (const float2*)(ws_fc + (size_t)idx * 16);
        float o0 = bfc[0], o1 = bfc[1];
        #pragma unroll
        for (int w = 0; w < 8; ++w) { o0 += p[w].x; o1 += p[w].y; }
        out[idx * 2 + 0] = o0;
        out[idx * 2 + 1] = o1;
    }
}

// ---- safety-net fallback (ws too small): dense branchy loops, inline FC ----
__global__ __launch_bounds__(512)
void dgru_raw(const float* __restrict__ x,
              const float* __restrict__ wih0, const float* __restrict__ whh0,
              const float* __restrict__ wih1, const float* __restrict__ whh1,
              const float* __restrict__ bih0, const float* __restrict__ bhh0,
              const float* __restrict__ bih1, const float* __restrict__ bhh1,
              const float* __restrict__ wfc,  const float* __restrict__ bfc,
              float* __restrict__ out) {
    __shared__ float s_dx0[8];
    __shared__ float s_xp0[8];
    __shared__ float s_dh0[HID];
    __shared__ float s_dx1[HID];
    __shared__ float s_dh1[HID];
    __shared__ float s_part[16];

    const int j = threadIdx.x;
    const int b = blockIdx.x;
    float h0 = 0.f, h0p = 0.f, xp1 = 0.f, h1 = 0.f, h1p = 0.f;
    float cr0 = bih0[j] + bhh0[j];
    float cz0 = bih0[HID + j] + bhh0[HID + j];
    float cn0 = bih0[2*HID + j];
    float cnh0 = bhh0[2*HID + j];
    float cr1 = bih1[j] + bhh1[j];
    float cz1 = bih1[HID + j] + bhh1[HID + j];
    float cn1 = bih1[2*HID + j];
    float cnh1 = bhh1[2*HID + j];
    if (j < 8) { s_xp0[j] = 0.f; s_dx0[j] = 0.f; }
    const float wfc0 = wfc[j], wfc1 = wfc[HID + j];
    __syncthreads();

    for (int t = 0; t < NT; ++t) {
        float d = h0 - h0p;
        if (fabsf(d) < THH) d = 0.f; else h0p = h0;
        s_dh0[j] = d;
        if (j < 6) {
            float iv = x[(b * NT + t) * 2 + 0];
            float qv = x[(b * NT + t) * 2 + 1];
            float amp = sqrtf(iv * iv + qv * qv);
            float f;
            if      (j == 0) f = iv;
            else if (j == 1) f = qv;
            else if (j == 2) f = amp;
            else if (j == 3) f = amp * amp * amp;
            else if (j == 4) f = qv / amp;
            else             f = iv / amp;
            float dx = f - s_xp0[j];
            if (fabsf(dx) < THX) dx = 0.f; else s_xp0[j] = f;
            s_dx0[j] = dx;
        }
        __syncthreads();
        {
            float ar = cr0, az = cz0, an = cn0, anh = cnh0;
            #pragma unroll
            for (int f = 0; f < 6; ++f) {
                float dv = s_dx0[f];
                ar += dv * wih0[j * 6 + f];
                az += dv * wih0[(HID + j) * 6 + f];
                an += dv * wih0[(2*HID + j) * 6 + f];
            }
            for (int k = 0; k < HID; ++k) {
                float dv = s_dh0[k];
                if (dv != 0.f) {
                    ar  += dv * whh0[j * HID + k];
                    az  += dv * whh0[(HID + j) * HID + k];
                    anh += dv * whh0[(2*HID + j) * HID + k];
                }
            }
            cr0 = ar; cz0 = az; cn0 = an; cnh0 = anh;
            float r = 1.f / (1.f + expf(-ar));
            float z = 1.f / (1.f + expf(-az));
            float n = tanhf(an + r * anh);
            h0 = (1.f - z) * n + z * h0;
        }
        float dxv = h0 - xp1;
        if (fabsf(dxv) < THX) dxv = 0.f; else xp1 = h0;
        s_dx1[j] = dxv;
        float dhv = h1 - h1p;
        if (fabsf(dhv) < THH) dhv = 0.f; else h1p = h1;
        s_dh1[j] = dhv;
        __syncthreads();
        {
            float ar = cr1, az = cz1, an = cn1, anh = cnh1;
            for (int k = 0; k < HID; ++k) {
                float dv = s_dx1[k];
                if (dv != 0.f) {
                    ar += dv * wih1[j * HID + k];
                    az += dv * wih1[(HID + j) * HID + k];
                    an += dv * wih1[(2*HID + j) * HID + k];
                }
            }
            for (int k = 0; k < HID; ++k) {
                float dv = s_dh1[k];
                if (dv != 0.f) {
                    ar  += dv * whh1[j * HID + k];
                    az  += dv * whh1[(HID + j) * HID + k];
                    anh += dv * whh1[(2*HID + j) * HID + k];
                }
            }
            cr1 = ar; cz1 = az; cn1 = an; cnh1 = anh;
            float r = 1.f / (1.f + expf(-ar));
            float z = 1.f / (1.f + expf(-az));
            float n = tanhf(an + r * anh);
            h1 = (1.f - z) * n + z * h1;
        }
        float p0 = h1 * wfc0, p1 = h1 * wfc1;
        #pragma unroll
        for (int off = 32; off > 0; off >>= 1) {
            p0 += __shfl_down(p0, off, 64);
            p1 += __shfl_down(p1, off, 64);
        }
        if ((j & 63) == 0) { s_part[(j >> 6) * 2] = p0; s_part[(j >> 6) * 2 + 1] = p1; }
        __syncthreads();
        if (j == 0) {
            float o0 = bfc[0], o1 = bfc[1];
            #pragma unroll
            for (int w = 0; w < 8; ++w) { o0 += s_part[w * 2]; o1 += s_part[w * 2 + 1]; }
            out[(b * NT + t) * 2 + 0] = o0;
            out[(b * NT + t) * 2 + 1] = o1;
        }
    }
}

extern "C" void kernel_launch(void* const* d_in, const int* in_sizes, int n_in,
                              void* d_out, int out_size, void* d_ws, size_t ws_size,
                              hipStream_t stream) {
    const float* x    = (const float*)d_in[0];
    // d_in[1] = h_0 : reference zero-inits h, input unused
    const float* wih0 = (const float*)d_in[2];
    const float* whh0 = (const float*)d_in[3];
    const float* bih0 = (const float*)d_in[4];
    const float* bhh0 = (const float*)d_in[5];
    const float* wih1 = (const float*)d_in[6];
    const float* whh1 = (const float*)d_in[7];
    const float* bih1 = (const float*)d_in[8];
    const float* bhh1 = (const float*)d_in[9];
    const float* wfc  = (const float*)d_in[10];
    const float* bfc  = (const float*)d_in[11];
    float* out = (float*)d_out;

    const size_t MAT3  = (size_t)HID * 1536 * sizeof(float);      // 3 MiB per packed matrix
    const size_t o_ih0 = 0;                                        // 36 KiB
    const size_t o_hh0 = 6 * 1536 * sizeof(float);
    const size_t o_ih1 = o_hh0 + MAT3;
    const size_t o_hh1 = o_ih1 + MAT3;
    const size_t o_fc  = o_hh1 + MAT3;
    const size_t FCB   = (size_t)NB * NT * 8 * 2 * sizeof(float);  // 4 MiB partials
    const size_t need  = o_fc + FCB;                               // ~13 MiB

    if (ws_size >= need) {
        float* wt_ih0 = (float*)((char*)d_ws + o_ih0);
        float* wt_hh0 = (float*)((char*)d_ws + o_hh0);
        float* wt_ih1 = (float*)((char*)d_ws + o_ih1);
        float* wt_hh1 = (float*)((char*)d_ws + o_hh1);
        float* ws_fc  = (float*)((char*)d_ws + o_fc);
        pack_ih0<<<(6 * HID + 255) / 256, 256, 0, stream>>>(wih0, wt_ih0);
        pack_h3<<<(HID * HID + 255) / 256, 256, 0, stream>>>(whh0, wt_hh0);
        pack_h3<<<(HID * HID + 255) / 256, 256, 0, stream>>>(wih1, wt_ih1);
        pack_h3<<<(HID * HID + 255) / 256, 256, 0, stream>>>(whh1, wt_hh1);
        dgru_pipe<<<NB, 1024, 0, stream>>>(x, wt_ih0, wt_hh0, wt_ih1, wt_hh1,
                                           bih0, bhh0, bih1, bhh1, wfc, ws_fc);
        fc_reduce<<<(NB * NT + 255) / 256, 256, 0, stream>>>(ws_fc, bfc, out);
    } else {
        dgru_raw<<<NB, HID, 0, stream>>>(x, wih0, whh0, wih1, whh1,
                                         bih0, bhh0, bih1, bhh1, wfc, bfc, out);
    }
}

// Round 7
// 70944.543 us; speedup vs baseline: 1.9798x; 1.0209x over previous
//
#include <hip/hip_runtime.h>

#define HID 512
#define NB  64
#define NT  1024
#define THX 0.1f
#define THH 0.05f

// ---- prep: pack W_ih_l0 [1536][6] f32 -> [6][512]{r,z,n} float3 ----
__global__ void pack_ih0(const float* __restrict__ src, float* __restrict__ dst) {
    int idx = blockIdx.x * blockDim.x + threadIdx.x;
    if (idx < 6 * HID) {
        int f = idx / HID, j = idx % HID;
        dst[f * 1536 + j * 3 + 0] = src[(0 * HID + j) * 6 + f];
        dst[f * 1536 + j * 3 + 1] = src[(1 * HID + j) * 6 + f];
        dst[f * 1536 + j * 3 + 2] = src[(2 * HID + j) * 6 + f];
    }
}

// ---- prep: pack a [1536][512] f32 matrix -> [512(k)][512(j)]{r,z,n} float3 ----
__global__ void pack_h3(const float* __restrict__ src, float* __restrict__ dst) {
    int idx = blockIdx.x * blockDim.x + threadIdx.x;
    if (idx < HID * HID) {
        int k = idx / HID, j = idx % HID;
        dst[k * 1536 + j * 3 + 0] = src[(0 * HID + j) * HID + k];
        dst[k * 1536 + j * 3 + 1] = src[(1 * HID + j) * HID + k];
        dst[k * 1536 + j * 3 + 2] = src[(2 * HID + j) * HID + k];
    }
}

// ---- sparse MAC with EXPLICIT 8-deep load batching ----
// lst: compacted (k,val), n multiple of 32 (pads are k=0,v=0 -> exact +0 adds).
// Batch: 8 LDS entry reads + 8 independent 12B global loads in flight, then FMAs.
// #pragma unroll 1 on the outer loop: 1024-thr WG caps VGPR at 128; a 2x
// unroll of the batched body would spill (rounds 4/5 lesson).
__device__ __forceinline__ void mac3(const uint2* __restrict__ lst, int n,
                                     const float* __restrict__ wp, int j,
                                     float& a0, float& a1, float& a2) {
    #pragma unroll 1
    for (int i = 0; i < n; i += 8) {
        float  v[8];
        float3 w[8];
        #pragma unroll
        for (int c = 0; c < 8; ++c) {
            uint2 e = lst[i + c];              // uniform LDS read (broadcast)
            v[c] = __uint_as_float(e.y);
            const float3* row = (const float3*)(wp + (size_t)e.x * 1536);
            w[c] = row[j];                     // independent 12B coalesced load
        }
        #pragma unroll
        for (int c = 0; c < 8; ++c) {
            a0 += v[c] * w[c].x;
            a1 += v[c] * w[c].y;
            a2 += v[c] * w[c].z;
        }
    }
}

// ---- main kernel: 1024 threads/WG, 2-stage layer pipeline ----
// group A (tid 0..511):   layer 0 at step t     (owns h0, xp0, xp1, L0 carries)
// group B (tid 512..1023): layer 1 at step t-1  (owns h1, L1 carries, FC)
__global__ __launch_bounds__(1024)
void dgru_pipe(const float* __restrict__ x,
               const float* __restrict__ wih0p,   // [6][512] float3
               const float* __restrict__ whh0p,   // [512][512] float3
               const float* __restrict__ wih1p,
               const float* __restrict__ whh1p,
               const float* __restrict__ bih0, const float* __restrict__ bhh0,
               const float* __restrict__ bih1, const float* __restrict__ bhh1,
               const float* __restrict__ wfc,
               float* __restrict__ ws_fc) {       // [B][T][8 waves][2] partials
    __shared__ float s_x[2 * NT];                 // 8 KB raw input
    __shared__ float s_dx0[8];
    __shared__ float s_xp0[8];
    __shared__ int   s_cntA[8], s_cntB[8], s_cntC[8];
    __shared__ uint2 s_listA[HID + 32];           // L0 dh list   (A-internal)
    __shared__ uint2 s_listB[2][HID + 32];        // L1 dx list   (A->B, dbuf)
    __shared__ uint2 s_listC[HID + 32];           // L1 dh list   (B-internal)

    const int tid  = threadIdx.x;
    const int grp  = tid >> 9;          // 0 = A (layer0), 1 = B (layer1)
    const int j    = tid & (HID - 1);
    const int lane = tid & 63;
    const int gw   = (tid >> 6) & 7;    // wave index within group
    const int b    = blockIdx.x;

    // group A state
    float h0 = 0.f, h0p = 0.f, xp1 = 0.f;
    float cr0 = 0.f, cz0 = 0.f, cn0 = 0.f, cnh0 = 0.f;
    // group B state
    float h1 = 0.f, h1p = 0.f;
    float cr1 = 0.f, cz1 = 0.f, cn1 = 0.f, cnh1 = 0.f;
    float wfc0 = 0.f, wfc1 = 0.f;

    if (grp == 0) {
        cr0  = bih0[j]       + bhh0[j];
        cz0  = bih0[HID + j] + bhh0[HID + j];
        cn0  = bih0[2*HID + j];
        cnh0 = bhh0[2*HID + j];
    } else {
        cr1  = bih1[j]       + bhh1[j];
        cz1  = bih1[HID + j] + bhh1[HID + j];
        cn1  = bih1[2*HID + j];
        cnh1 = bhh1[2*HID + j];
        wfc0 = wfc[j];
        wfc1 = wfc[HID + j];
    }
    if (tid < 8) { s_xp0[tid] = 0.f; s_dx0[tid] = 0.f; }
    for (int i = tid; i < 2 * NT; i += 1024) s_x[i] = x[b * 2 * NT + i];
    __syncthreads();

    for (int t = 0; t < NT; ++t) {
        // ===== seg1: A computes dh0 + input features, publishes counts =====
        float dA = 0.f; unsigned long long mA = 0;
        if (grp == 0) {
            dA = h0 - h0p;
            if (fabsf(dA) < THH) dA = 0.f; else h0p = h0;
            mA = __ballot(dA != 0.f);
            if (lane == 0) s_cntA[gw] = __popcll(mA);
            if (tid < 6) {
                float iv = s_x[2 * t], qv = s_x[2 * t + 1];
                float amp = sqrtf(iv * iv + qv * qv);
                float f;
                if      (tid == 0) f = iv;
                else if (tid == 1) f = qv;
                else if (tid == 2) f = amp;
                else if (tid == 3) f = amp * amp * amp;
                else if (tid == 4) f = qv / amp;
                else               f = iv / amp;
                float dx = f - s_xp0[tid];
                if (fabsf(dx) < THX) dx = 0.f; else s_xp0[tid] = f;
                s_dx0[tid] = dx;
            }
        }
        __syncthreads();                                       // BAR1
        // ===== seg2: A scatters listA ======================================
        int npadA = 0;
        if (grp == 0) {
            int baseA = 0, nnzA = 0;
            #pragma unroll
            for (int w = 0; w < 8; ++w) {
                int c = s_cntA[w];
                baseA += (w < gw) ? c : 0;
                nnzA += c;
            }
            if (dA != 0.f) {
                int pos = baseA + __popcll(mA & ((1ull << lane) - 1));
                s_listA[pos] = make_uint2((unsigned)j, __float_as_uint(dA));
            }
            npadA = (nnzA + 31) & ~31;
            if (j < npadA - nnzA) s_listA[nnzA + j] = make_uint2(0u, 0u);
        }
        __syncthreads();                                       // BAR2
        // ===== seg3: A: L0 MAC+gates ||| B: L1(t-1) MAC+gates+FC ===========
        float dB = 0.f; unsigned long long mB = 0;   // A's dx1 delta
        float dC = 0.f; unsigned long long mC = 0;   // B's dh1 delta
        if (grp == 0) {
            float ar = cr0, az = cz0, an = cn0, anh = cnh0;
            #pragma unroll
            for (int f = 0; f < 6; ++f) {            // dv==0 adds exact +0
                float dv = s_dx0[f];
                const float3* row = (const float3*)(wih0p + f * 1536);
                float3 w = row[j];
                ar += dv * w.x; az += dv * w.y; an += dv * w.z;
            }
            mac3(s_listA, npadA, whh0p, j, ar, az, anh);
            cr0 = ar; cz0 = az; cn0 = an; cnh0 = anh;
            float r = 1.f / (1.f + expf(-ar));
            float z = 1.f / (1.f + expf(-az));
            float n = tanhf(an + r * anh);
            h0 = (1.f - z) * n + z * h0;
            dB = h0 - xp1;                           // dx1 for L1 step t
            if (fabsf(dB) < THX) dB = 0.f; else xp1 = h0;
            mB = __ballot(dB != 0.f);
            if (lane == 0) s_cntB[gw] = __popcll(mB);
        } else {
            if (t > 0) {
                float ar = cr1, az = cz1, an = cn1, anh = cnh1;
                int nB = 0, nC = 0;
                #pragma unroll
                for (int w = 0; w < 8; ++w) { nB += s_cntB[w]; nC += s_cntC[w]; }
                nB = (nB + 31) & ~31;
                nC = (nC + 31) & ~31;
                mac3(s_listB[(t - 1) & 1], nB, wih1p, j, ar, az, an);
                mac3(s_listC, nC, whh1p, j, ar, az, anh);
                cr1 = ar; cz1 = az; cn1 = an; cnh1 = anh;
                float r = 1.f / (1.f + expf(-ar));
                float z = 1.f / (1.f + expf(-az));
                float n = tanhf(an + r * anh);
                h1 = (1.f - z) * n + z * h1;
                float p0 = h1 * wfc0, p1 = h1 * wfc1;
                #pragma unroll
                for (int off = 32; off > 0; off >>= 1) {
                    p0 += __shfl_down(p0, off, 64);
                    p1 += __shfl_down(p1, off, 64);
                }
                if (lane == 0) {
                    float2* dst = (float2*)(ws_fc + ((size_t)(b * NT + (t - 1)) * 8 + gw) * 2);
                    *dst = make_float2(p0, p1);
                }
            }
            dC = h1 - h1p;                           // dh1 for L1 step t
            if (fabsf(dC) < THH) dC = 0.f; else h1p = h1;
            mC = __ballot(dC != 0.f);
            if (lane == 0) s_cntC[gw] = __popcll(mC);
        }
        __syncthreads();                                       // BAR3
        // ===== seg4: scatter listB (A) and listC (B) =======================
        if (grp == 0) {
            int baseB = 0, nnzB = 0;
            #pragma unroll
            for (int w = 0; w < 8; ++w) {
                int c = s_cntB[w];
                baseB += (w < gw) ? c : 0;
                nnzB += c;
            }
            if (dB != 0.f) {
                int pos = baseB + __popcll(mB & ((1ull << lane) - 1));
                s_listB[t & 1][pos] = make_uint2((unsigned)j, __float_as_uint(dB));
            }
            int npadB = (nnzB + 31) & ~31;
            if (j < npadB - nnzB) s_listB[t & 1][nnzB + j] = make_uint2(0u, 0u);
        } else {
            int baseC = 0, nnzC = 0;
            #pragma unroll
            for (int w = 0; w < 8; ++w) {
                int c = s_cntC[w];
                baseC += (w < gw) ? c : 0;
                nnzC += c;
            }
            if (dC != 0.f) {
                int pos = baseC + __popcll(mC & ((1ull << lane) - 1));
                s_listC[pos] = make_uint2((unsigned)j, __float_as_uint(dC));
            }
            int npadC = (nnzC + 31) & ~31;
            if (j < npadC - nnzC) s_listC[nnzC + j] = make_uint2(0u, 0u);
        }
        __syncthreads();                                       // BAR4
    }

    // ===== epilogue: B runs L1 for step NT-1 ===============================
    if (grp == 1) {
        float ar = cr1, az = cz1, an = cn1, anh = cnh1;
        int nB = 0, nC = 0;
        #pragma unroll
        for (int w = 0; w < 8; ++w) { nB += s_cntB[w]; nC += s_cntC[w]; }
        nB = (nB + 31) & ~31;
        nC = (nC + 31) & ~31;
        mac3(s_listB[(NT - 1) & 1], nB, wih1p, j, ar, az, an);
        mac3(s_listC, nC, whh1p, j, ar, az, anh);
        float r = 1.f / (1.f + expf(-ar));
        float z = 1.f / (1.f + expf(-az));
        float n = tanhf(an + r * anh);
        h1 = (1.f - z) * n + z * h1;
        float p0 = h1 * wfc0, p1 = h1 * wfc1;
        #pragma unroll
        for (int off = 32; off > 0; off >>= 1) {
            p0 += __shfl_down(p0, off, 64);
            p1 += __shfl_down(p1, off, 64);
        }
        if (lane == 0) {
            float2* dst = (float2*)(ws_fc + ((size_t)(b * NT + (NT - 1)) * 8 + gw) * 2);
            *dst = make_float2(p0, p1);
        }
    }
}

// ---- epilogue: deterministic ascending-wave FC reduction ----
__global__ void fc_reduce(const float* __restrict__ ws_fc,
                          const float* __restrict__ bfc,
                          float* __restrict__ out) {
    int idx = blockIdx.x * blockDim.x + threadIdx.x;   // (b*NT + t)
    if (idx < NB * NT) {
        const float2* p = (const float2*)(ws_fc + (size_t)idx * 16);
        float o0 = bfc[0], o1 = bfc[1];
        #pragma unroll
        for (int w = 0; w < 8; ++w) { o0 += p[w].x; o1 += p[w].y; }
        out[idx * 2 + 0] = o0;
        out[idx * 2 + 1] = o1;
    }
}

// ---- safety-net fallback (ws too small): dense branchy loops, inline FC ----
__global__ __launch_bounds__(512)
void dgru_raw(const float* __restrict__ x,
              const float* __restrict__ wih0, const float* __restrict__ whh0,
              const float* __restrict__ wih1, const float* __restrict__ whh1,
              const float* __restrict__ bih0, const float* __restrict__ bhh0,
              const float* __restrict__ bih1, const float* __restrict__ bhh1,
              const float* __restrict__ wfc,  const float* __restrict__ bfc,
              float* __restrict__ out) {
    __shared__ float s_dx0[8];
    __shared__ float s_xp0[8];
    __shared__ float s_dh0[HID];
    __shared__ float s_dx1[HID];
    __shared__ float s_dh1[HID];
    __shared__ float s_part[16];

    const int j = threadIdx.x;
    const int b = blockIdx.x;
    float h0 = 0.f, h0p = 0.f, xp1 = 0.f, h1 = 0.f, h1p = 0.f;
    float cr0 = bih0[j] + bhh0[j];
    float cz0 = bih0[HID + j] + bhh0[HID + j];
    float cn0 = bih0[2*HID + j];
    float cnh0 = bhh0[2*HID + j];
    float cr1 = bih1[j] + bhh1[j];
    float cz1 = bih1[HID + j] + bhh1[HID + j];
    float cn1 = bih1[2*HID + j];
    float cnh1 = bhh1[2*HID + j];
    if (j < 8) { s_xp0[j] = 0.f; s_dx0[j] = 0.f; }
    const float wfc0 = wfc[j], wfc1 = wfc[HID + j];
    __syncthreads();

    for (int t = 0; t < NT; ++t) {
        float d = h0 - h0p;
        if (fabsf(d) < THH) d = 0.f; else h0p = h0;
        s_dh0[j] = d;
        if (j < 6) {
            float iv = x[(b * NT + t) * 2 + 0];
            float qv = x[(b * NT + t) * 2 + 1];
            float amp = sqrtf(iv * iv + qv * qv);
            float f;
            if      (j == 0) f = iv;
            else if (j == 1) f = qv;
            else if (j == 2) f = amp;
            else if (j == 3) f = amp * amp * amp;
            else if (j == 4) f = qv / amp;
            else             f = iv / amp;
            float dx = f - s_xp0[j];
            if (fabsf(dx) < THX) dx = 0.f; else s_xp0[j] = f;
            s_dx0[j] = dx;
        }
        __syncthreads();
        {
            float ar = cr0, az = cz0, an = cn0, anh = cnh0;
            #pragma unroll
            for (int f = 0; f < 6; ++f) {
                float dv = s_dx0[f];
                ar += dv * wih0[j * 6 + f];
                az += dv * wih0[(HID + j) * 6 + f];
                an += dv * wih0[(2*HID + j) * 6 + f];
            }
            for (int k = 0; k < HID; ++k) {
                float dv = s_dh0[k];
                if (dv != 0.f) {
                    ar  += dv * whh0[j * HID + k];
                    az  += dv * whh0[(HID + j) * HID + k];
                    anh += dv * whh0[(2*HID + j) * HID + k];
                }
            }
            cr0 = ar; cz0 = az; cn0 = an; cnh0 = anh;
            float r = 1.f / (1.f + expf(-ar));
            float z = 1.f / (1.f + expf(-az));
            float n = tanhf(an + r * anh);
            h0 = (1.f - z) * n + z * h0;
        }
        float dxv = h0 - xp1;
        if (fabsf(dxv) < THX) dxv = 0.f; else xp1 = h0;
        s_dx1[j] = dxv;
        float dhv = h1 - h1p;
        if (fabsf(dhv) < THH) dhv = 0.f; else h1p = h1;
        s_dh1[j] = dhv;
        __syncthreads();
        {
            float ar = cr1, az = cz1, an = cn1, anh = cnh1;
            for (int k = 0; k < HID; ++k) {
                float dv = s_dx1[k];
                if (dv != 0.f) {
                    ar += dv * wih1[j * HID + k];
                    az += dv * wih1[(HID + j) * HID + k];
                    an += dv * wih1[(2*HID + j) * HID + k];
                }
            }
            for (int k = 0; k < HID; ++k) {
                float dv = s_dh1[k];
                if (dv != 0.f) {
                    ar  += dv * whh1[j * HID + k];
                    az  += dv * whh1[(HID + j) * HID + k];
                    anh += dv * whh1[(2*HID + j) * HID + k];
                }
            }
            cr1 = ar; cz1 = az; cn1 = an; cnh1 = anh;
            float r = 1.f / (1.f + expf(-ar));
            float z = 1.f / (1.f + expf(-az));
            float n = tanhf(an + r * anh);
            h1 = (1.f - z) * n + z * h1;
        }
        float p0 = h1 * wfc0, p1 = h1 * wfc1;
        #pragma unroll
        for (int off = 32; off > 0; off >>= 1) {
            p0 += __shfl_down(p0, off, 64);
            p1 += __shfl_down(p1, off, 64);
        }
        if ((j & 63) == 0) { s_part[(j >> 6) * 2] = p0; s_part[(j >> 6) * 2 + 1] = p1; }
        __syncthreads();
        if (j == 0) {
            float o0 = bfc[0], o1 = bfc[1];
            #pragma unroll
            for (int w = 0; w < 8; ++w) { o0 += s_part[w * 2]; o1 += s_part[w * 2 + 1]; }
            out[(b * NT + t) * 2 + 0] = o0;
            out[(b * NT + t) * 2 + 1] = o1;
        }
    }
}

extern "C" void kernel_launch(void* const* d_in, const int* in_sizes, int n_in,
                              void* d_out, int out_size, void* d_ws, size_t ws_size,
                              hipStream_t stream) {
    const float* x    = (const float*)d_in[0];
    // d_in[1] = h_0 : reference zero-inits h, input unused
    const float* wih0 = (const float*)d_in[2];
    const float* whh0 = (const float*)d_in[3];
    const float* bih0 = (const float*)d_in[4];
    const float* bhh0 = (const float*)d_in[5];
    const float* wih1 = (const float*)d_in[6];
    const float* whh1 = (const float*)d_in[7];
    const float* bih1 = (const float*)d_in[8];
    const float* bhh1 = (const float*)d_in[9];
    const float* wfc  = (const float*)d_in[10];
    const float* bfc  = (const float*)d_in[11];
    float* out = (float*)d_out;

    const size_t MAT3  = (size_t)HID * 1536 * sizeof(float);      // 3 MiB per packed matrix
    const size_t o_ih0 = 0;                                        // 36 KiB
    const size_t o_hh0 = 6 * 1536 * sizeof(float);
    const size_t o_ih1 = o_hh0 + MAT3;
    const size_t o_hh1 = o_ih1 + MAT3;
    const size_t o_fc  = o_hh1 + MAT3;
    const size_t FCB   = (size_t)NB * NT * 8 * 2 * sizeof(float);  // 4 MiB partials
    const size_t need  = o_fc + FCB;                               // ~13 MiB

    if (ws_size >= need) {
        float* wt_ih0 = (float*)((char*)d_ws + o_ih0);
        float* wt_hh0 = (float*)((char*)d_ws + o_hh0);
        float* wt_ih1 = (float*)((char*)d_ws + o_ih1);
        float* wt_hh1 = (float*)((char*)d_ws + o_hh1);
        float* ws_fc  = (float*)((char*)d_ws + o_fc);
        pack_ih0<<<(6 * HID + 255) / 256, 256, 0, stream>>>(wih0, wt_ih0);
        pack_h3<<<(HID * HID + 255) / 256, 256, 0, stream>>>(whh0, wt_hh0);
        pack_h3<<<(HID * HID + 255) / 256, 256, 0, stream>>>(wih1, wt_ih1);
        pack_h3<<<(HID * HID + 255) / 256, 256, 0, stream>>>(whh1, wt_hh1);
        dgru_pipe<<<NB, 1024, 0, stream>>>(x, wt_ih0, wt_hh0, wt_ih1, wt_hh1,
                                           bih0, bhh0, bih1, bhh1, wfc, ws_fc);
        fc_reduce<<<(NB * NT + 255) / 256, 256, 0, stream>>>(ws_fc, bfc, out);
    } else {
        dgru_raw<<<NB, HID, 0, stream>>>(x, wih0, whh0, wih1, whh1,
                                         bih0, bhh0, bih1, bhh1, wfc, bfc, out);
    }
}